// Round 8
// baseline (977.686 us; speedup 1.0000x reference)
//
#include <hip/hip_runtime.h>

// SimpleRetention R8: B=131072 batches of 14x14 fp32, 4 sequential 7x7
// chunks with carried state r.
// R1-R7 root cause: every amplified-traffic round was REGISTER SPILL.
// Small-workgroup kernels default to a 4-waves/EU occupancy target ->
// 128-VGPR cap; live set ~190 -> ~60 spilled dwords/thread re-filled in
// the d-loop -> 100s of MB scratch traffic. __launch_bounds__/waves_per_eu
// attempts did NOT lift the cap (VGPR_Count stayed 128).
// R8 = R7 with NO occupancy attributes at all: allocator grows to the live
// set (~190 VGPR), zero spill. LDS caps residency at 6 blocks/CU.
//  - input: lane-contiguous float2 loads -> LDS (R2-proven ~1x traffic)
//  - compute: x rows read on demand from LDS; K,V,r in regs
//  - output: o rows overwrite dead x slots; lane-contiguous float2 stores
//  - 1-wave blocks: zero barriers (same-wave DS ops are in-order)

#define CS 7
#define NT 64
#define F2PH 49   // float2 per batch per half
#define LDSW 98   // floats per batch in LDS

// Block region: 64 batches x 98 float2. Half H of batch bl = float2
// [bl*98 + H*49, +49). Staging index lin = k*64 + t -> bl = lin/49,
// e = lin%49, global float2 g = lin + (bl + H)*49.
// lin += 64 => e += 15 (wrap: -49, bl extra +1): g += 113 or 162.
template <int H>
__device__ __forceinline__ void load_half(const float2* __restrict__ X2,
                                          float2* __restrict__ xs2, int t) {
    int e = (t >= F2PH) ? t - F2PH : t;
    int g = (t >= F2PH) ? t + F2PH * (1 + H) : t + F2PH * H;
#pragma unroll
    for (int k = 0; k < F2PH; ++k) {
        xs2[k * NT + t] = X2[g];    // load feeds ds_write; scheduler batches
        if (k < F2PH - 1) {
            e += 15;
            int w = (e >= F2PH);
            e -= w ? F2PH : 0;
            g += w ? 162 : 113;
        }
    }
}

template <int H>
__device__ __forceinline__ void store_half(float2* __restrict__ O2,
                                           const float2* __restrict__ xs2,
                                           int t) {
    int e = (t >= F2PH) ? t - F2PH : t;
    int g = (t >= F2PH) ? t + F2PH * (1 + H) : t + F2PH * H;
#pragma unroll
    for (int k = 0; k < F2PH; ++k) {
        O2[g] = xs2[k * NT + t];
        if (k < F2PH - 1) {
            e += 15;
            int w = (e >= F2PH);
            e -= w ? F2PH : 0;
            g += w ? 162 : 113;
        }
    }
}

template <int C>
__device__ __forceinline__ void chunk(float* __restrict__ xrow, float r[49],
                                      const float* __restrict__ WQ,
                                      const float* __restrict__ WK,
                                      const float* __restrict__ WV,
                                      const float* __restrict__ Dm) {
    constexpr int CO = (C & 1) * CS;    // col offset within 14-wide row
    constexpr int RO = (C >> 1) * CS;   // global row offset (for D)
    const float* wq = WQ + C * 49;      // wave-uniform -> s_load
    const float* wk = WK + C * 49;
    const float* wv = WV + C * 49;

    // K,V row-by-row from LDS x rows (x never fully register-resident)
    float K[49], V[49];
#pragma unroll
    for (int i = 0; i < CS; ++i) {
        float xr[CS];
#pragma unroll
        for (int k = 0; k < CS; ++k) xr[k] = xrow[i * 14 + CO + k];
#pragma unroll
        for (int j = 0; j < CS; ++j) {
            float ak = 0.f, av = 0.f;
#pragma unroll
            for (int k = 0; k < CS; ++k) {
                ak = fmaf(xr[k], wk[k * CS + j], ak);
                av = fmaf(xr[k], wv[k * CS + j], av);
            }
            K[i * CS + j] = ak;
            V[i * CS + j] = av;
        }
    }

    // per output row d: q (x row d re-read from LDS) -> s -> cross -> o
#pragma unroll
    for (int d = 0; d < CS; ++d) {
        const float ev = (d == 0) ? 0.2f : (d == 1) ? 0.04f : (d == 2) ? 0.008f
                        : (d == 3) ? 0.0016f : (d == 4) ? 3.2e-4f
                        : (d == 5) ? 6.4e-5f : 1.28e-5f;
        float xr[CS];
#pragma unroll
        for (int k = 0; k < CS; ++k) xr[k] = xrow[d * 14 + CO + k];
        float q[CS];
#pragma unroll
        for (int j = 0; j < CS; ++j) {
            float a = 0.f;
#pragma unroll
            for (int k = 0; k < CS; ++k)
                a = fmaf(xr[k], wq[k * CS + j], a);
            q[j] = a;
        }
        float s[CS];
#pragma unroll
        for (int k = 0; k < CS; ++k) {
            float a = 0.f;
#pragma unroll
            for (int j = 0; j < CS; ++j) a = fmaf(q[j], K[k * CS + j], a);
            s[k] = a * Dm[(RO + d) * 14 + CO + k];   // uniform -> s_load
        }
        float o[CS];
#pragma unroll
        for (int v = 0; v < CS; ++v) {
            float a = 0.f;
#pragma unroll
            for (int j = 0; j < CS; ++j) a = fmaf(q[j], r[j * CS + v], a);
            o[v] = ev * a;
        }
#pragma unroll
        for (int k = 0; k < CS; ++k)
#pragma unroll
            for (int v = 0; v < CS; ++v)
                o[v] = fmaf(s[k], V[k * CS + v], o[v]);
        // overwrite own-column slots of x row d (dead for this chunk; the
        // sibling chunk uses the other 7 columns)
#pragma unroll
        for (int v = 0; v < CS; ++v)
            xrow[d * 14 + CO + v] = o[v];
    }

    // r += K^T V
#pragma unroll
    for (int dd = 0; dd < CS; ++dd)
#pragma unroll
        for (int v = 0; v < CS; ++v) {
            float a = r[dd * CS + v];
#pragma unroll
            for (int k = 0; k < CS; ++k)
                a = fmaf(K[k * CS + dd], V[k * CS + v], a);
            r[dd * CS + v] = a;
        }
}

__global__ void retention_kernel(const float* __restrict__ X,
                                 const float* __restrict__ WQ,
                                 const float* __restrict__ WK,
                                 const float* __restrict__ WV,
                                 const float* __restrict__ Dm,
                                 float* __restrict__ Out) {
    __shared__ float xs[NT * LDSW];   // 25088 B -> 6 blocks/CU
    const int t = threadIdx.x;
    const size_t breg = (size_t)blockIdx.x * (NT * F2PH * 2);  // float2 units
    const float2* X2 = reinterpret_cast<const float2*>(X) + breg;
    float2*       O2 = reinterpret_cast<float2*>(Out) + breg;
    float2* xs2 = reinterpret_cast<float2*>(xs);
    float* xrow = xs + t * LDSW;

    float r[49];
#pragma unroll
    for (int i = 0; i < 49; ++i) r[i] = 0.f;

    load_half<0>(X2, xs2, t);
    chunk<0>(xrow, r, WQ, WK, WV, Dm);
    chunk<1>(xrow, r, WQ, WK, WV, Dm);
    store_half<0>(O2, xs2, t);

    load_half<1>(X2, xs2, t);
    chunk<2>(xrow, r, WQ, WK, WV, Dm);
    chunk<3>(xrow, r, WQ, WK, WV, Dm);
    store_half<1>(O2, xs2, t);
}

extern "C" void kernel_launch(void* const* d_in, const int* in_sizes, int n_in,
                              void* d_out, int out_size, void* d_ws, size_t ws_size,
                              hipStream_t stream) {
    const float* X  = (const float*)d_in[0];
    const float* WQ = (const float*)d_in[1];
    const float* WK = (const float*)d_in[2];
    const float* WV = (const float*)d_in[3];
    const float* Dm = (const float*)d_in[4];
    float* Out = (float*)d_out;

    int B = in_sizes[0] / 196;   // 131072, divisible by 64
    int grid = B / NT;
    retention_kernel<<<grid, NT, 0, stream>>>(X, WQ, WK, WV, Dm, Out);
}

// Round 9
// 204.345 us; speedup vs baseline: 4.7845x; 4.7845x over previous
//
#include <hip/hip_runtime.h>

// SimpleRetention R9: B=131072 batches of 14x14 fp32, 4 sequential 7x7
// chunks with carried state r.
// R1-R8 root cause: register-spill scratch traffic. VGPR budget vs traffic:
//   64 VGPR -> 1.8 GB, 128 -> 0.9 GB, 144 -> ~0.17 GB (clean).
// LLVM targets the MAX of amdgpu-waves-per-eu: R7's (2,4) -> 512/4 = 128.
// R9 sets (1,2) -> budget 256 >= live set (~190) -> ZERO spill.
// Structure unchanged from R8 (proven math + R2-proven lane-contiguous
// float2 I/O):
//  - input: lane-contiguous float2 loads -> LDS
//  - compute: x rows on demand from LDS; K,V,r in regs
//  - output: o rows overwrite dead x slots; lane-contiguous float2 stores
//  - 1-wave blocks: zero barriers (same-wave DS ops are in-order)
//  - 25KB LDS -> 6 blocks/CU

#define CS 7
#define NT 64
#define F2PH 49   // float2 per batch per half
#define LDSW 98   // floats per batch in LDS

// Block region: 64 batches x 98 float2. Half H of batch bl = float2
// [bl*98 + H*49, +49). Staging index lin = k*64 + t -> bl = lin/49,
// e = lin%49, global float2 g = lin + (bl + H)*49.
// lin += 64 => e += 15 (wrap: -49, bl extra +1): g += 113 or 162.
template <int H>
__device__ __forceinline__ void load_half(const float2* __restrict__ X2,
                                          float2* __restrict__ xs2, int t) {
    int e = (t >= F2PH) ? t - F2PH : t;
    int g = (t >= F2PH) ? t + F2PH * (1 + H) : t + F2PH * H;
#pragma unroll
    for (int k = 0; k < F2PH; ++k) {
        xs2[k * NT + t] = X2[g];    // load feeds ds_write; scheduler batches
        if (k < F2PH - 1) {
            e += 15;
            int w = (e >= F2PH);
            e -= w ? F2PH : 0;
            g += w ? 162 : 113;
        }
    }
}

template <int H>
__device__ __forceinline__ void store_half(float2* __restrict__ O2,
                                           const float2* __restrict__ xs2,
                                           int t) {
    int e = (t >= F2PH) ? t - F2PH : t;
    int g = (t >= F2PH) ? t + F2PH * (1 + H) : t + F2PH * H;
#pragma unroll
    for (int k = 0; k < F2PH; ++k) {
        O2[g] = xs2[k * NT + t];
        if (k < F2PH - 1) {
            e += 15;
            int w = (e >= F2PH);
            e -= w ? F2PH : 0;
            g += w ? 162 : 113;
        }
    }
}

template <int C>
__device__ __forceinline__ void chunk(float* __restrict__ xrow, float r[49],
                                      const float* __restrict__ WQ,
                                      const float* __restrict__ WK,
                                      const float* __restrict__ WV,
                                      const float* __restrict__ Dm) {
    constexpr int CO = (C & 1) * CS;    // col offset within 14-wide row
    constexpr int RO = (C >> 1) * CS;   // global row offset (for D)
    const float* wq = WQ + C * 49;      // wave-uniform -> s_load
    const float* wk = WK + C * 49;
    const float* wv = WV + C * 49;

    // K,V row-by-row from LDS x rows (x never fully register-resident)
    float K[49], V[49];
#pragma unroll
    for (int i = 0; i < CS; ++i) {
        float xr[CS];
#pragma unroll
        for (int k = 0; k < CS; ++k) xr[k] = xrow[i * 14 + CO + k];
#pragma unroll
        for (int j = 0; j < CS; ++j) {
            float ak = 0.f, av = 0.f;
#pragma unroll
            for (int k = 0; k < CS; ++k) {
                ak = fmaf(xr[k], wk[k * CS + j], ak);
                av = fmaf(xr[k], wv[k * CS + j], av);
            }
            K[i * CS + j] = ak;
            V[i * CS + j] = av;
        }
    }

    // per output row d: q (x row d re-read from LDS) -> s -> cross -> o
#pragma unroll
    for (int d = 0; d < CS; ++d) {
        const float ev = (d == 0) ? 0.2f : (d == 1) ? 0.04f : (d == 2) ? 0.008f
                        : (d == 3) ? 0.0016f : (d == 4) ? 3.2e-4f
                        : (d == 5) ? 6.4e-5f : 1.28e-5f;
        float xr[CS];
#pragma unroll
        for (int k = 0; k < CS; ++k) xr[k] = xrow[d * 14 + CO + k];
        float q[CS];
#pragma unroll
        for (int j = 0; j < CS; ++j) {
            float a = 0.f;
#pragma unroll
            for (int k = 0; k < CS; ++k)
                a = fmaf(xr[k], wq[k * CS + j], a);
            q[j] = a;
        }
        float s[CS];
#pragma unroll
        for (int k = 0; k < CS; ++k) {
            float a = 0.f;
#pragma unroll
            for (int j = 0; j < CS; ++j) a = fmaf(q[j], K[k * CS + j], a);
            s[k] = a * Dm[(RO + d) * 14 + CO + k];   // uniform -> s_load
        }
        float o[CS];
#pragma unroll
        for (int v = 0; v < CS; ++v) {
            float a = 0.f;
#pragma unroll
            for (int j = 0; j < CS; ++j) a = fmaf(q[j], r[j * CS + v], a);
            o[v] = ev * a;
        }
#pragma unroll
        for (int k = 0; k < CS; ++k)
#pragma unroll
            for (int v = 0; v < CS; ++v)
                o[v] = fmaf(s[k], V[k * CS + v], o[v]);
        // overwrite own-column slots of x row d (dead for this chunk; the
        // sibling chunk uses the other 7 columns)
#pragma unroll
        for (int v = 0; v < CS; ++v)
            xrow[d * 14 + CO + v] = o[v];
    }

    // r += K^T V
#pragma unroll
    for (int dd = 0; dd < CS; ++dd)
#pragma unroll
        for (int v = 0; v < CS; ++v) {
            float a = r[dd * CS + v];
#pragma unroll
            for (int k = 0; k < CS; ++k)
                a = fmaf(K[k * CS + dd], V[k * CS + v], a);
            r[dd * CS + v] = a;
        }
}

__global__ __launch_bounds__(NT)
__attribute__((amdgpu_waves_per_eu(1, 2)))   // budget 512/2=256 -> no spill
void retention_kernel(const float* __restrict__ X,
                      const float* __restrict__ WQ,
                      const float* __restrict__ WK,
                      const float* __restrict__ WV,
                      const float* __restrict__ Dm,
                      float* __restrict__ Out) {
    __shared__ float xs[NT * LDSW];   // 25088 B -> 6 blocks/CU
    const int t = threadIdx.x;
    const size_t breg = (size_t)blockIdx.x * (NT * F2PH * 2);  // float2 units
    const float2* X2 = reinterpret_cast<const float2*>(X) + breg;
    float2*       O2 = reinterpret_cast<float2*>(Out) + breg;
    float2* xs2 = reinterpret_cast<float2*>(xs);
    float* xrow = xs + t * LDSW;

    float r[49];
#pragma unroll
    for (int i = 0; i < 49; ++i) r[i] = 0.f;

    load_half<0>(X2, xs2, t);
    chunk<0>(xrow, r, WQ, WK, WV, Dm);
    chunk<1>(xrow, r, WQ, WK, WV, Dm);
    store_half<0>(O2, xs2, t);

    load_half<1>(X2, xs2, t);
    chunk<2>(xrow, r, WQ, WK, WV, Dm);
    chunk<3>(xrow, r, WQ, WK, WV, Dm);
    store_half<1>(O2, xs2, t);
}

extern "C" void kernel_launch(void* const* d_in, const int* in_sizes, int n_in,
                              void* d_out, int out_size, void* d_ws, size_t ws_size,
                              hipStream_t stream) {
    const float* X  = (const float*)d_in[0];
    const float* WQ = (const float*)d_in[1];
    const float* WK = (const float*)d_in[2];
    const float* WV = (const float*)d_in[3];
    const float* Dm = (const float*)d_in[4];
    float* Out = (float*)d_out;

    int B = in_sizes[0] / 196;   // 131072, divisible by 64
    int grid = B / NT;
    retention_kernel<<<grid, NT, 0, stream>>>(X, WQ, WK, WV, Dm, Out);
}

// Round 10
// 178.416 us; speedup vs baseline: 5.4798x; 1.1453x over previous
//
#include <hip/hip_runtime.h>

// SimpleRetention R10: B=131072 batches of 14x14 fp32, 4 sequential 7x7
// chunks with carried state r.
// R1-R9 established: ALL HBM amplification was register-spill scratch
// traffic; allocator budget = 512 / max(waves_per_eu). R9 (budget 256)
// still spilled ~70 dwords/chunk (staging loads + compute live > 256):
// WRITE 251 MB (dirty scratch evictions), FETCH clean (scratch refills hit
// L2). R10:
//  - amdgpu_waves_per_eu(1,1): budget 512 >= true peak (~320) -> NO spill
//  - half-1 prefetched into REGISTERS under half-0 compute (latency hidden),
//    written to LDS after store_half<0>'s in-order DS reads
//  - x in registers per chunk (single LDS read pass)
//  - lane-contiguous float2 global I/O (R2-proven ~1x traffic), 1-wave
//    blocks, zero barriers (same-wave DS ops are in-order)

#define CS 7
#define NT 64
#define F2PH 49   // float2 per batch per half
#define LDSW 98   // floats per batch in LDS

// Block region: 64 batches x 98 float2. Half H of batch bl = float2
// [bl*98 + H*49, +49). Staging index lin = k*64 + t -> bl = lin/49,
// e = lin%49, global float2 g = lin + (bl + H)*49.
// lin += 64 => e += 15 (wrap: -49, bl extra +1): g += 113 or 162.
#define STAGE_IDX_INIT(H)                                   \
    int e = (t >= F2PH) ? t - F2PH : t;                     \
    int g = (t >= F2PH) ? t + F2PH * (1 + (H)) : t + F2PH * (H);
#define STAGE_IDX_STEP()                                    \
    { e += 15; int w = (e >= F2PH); e -= w ? F2PH : 0; g += w ? 162 : 113; }

template <int H>
__device__ __forceinline__ void load_half(const float2* __restrict__ X2,
                                          float2* __restrict__ xs2, int t) {
    STAGE_IDX_INIT(H)
#pragma unroll
    for (int k = 0; k < F2PH; ++k) {
        xs2[k * NT + t] = X2[g];
        if (k < F2PH - 1) STAGE_IDX_STEP()
    }
}

template <int H>
__device__ __forceinline__ void load_regs(const float2* __restrict__ X2,
                                          float2 v[F2PH], int t) {
    STAGE_IDX_INIT(H)
#pragma unroll
    for (int k = 0; k < F2PH; ++k) {
        v[k] = X2[g];
        if (k < F2PH - 1) STAGE_IDX_STEP()
    }
}

__device__ __forceinline__ void write_half(float2* __restrict__ xs2,
                                           const float2 v[F2PH], int t) {
#pragma unroll
    for (int k = 0; k < F2PH; ++k)
        xs2[k * NT + t] = v[k];
}

template <int H>
__device__ __forceinline__ void store_half(float2* __restrict__ O2,
                                           const float2* __restrict__ xs2,
                                           int t) {
    STAGE_IDX_INIT(H)
#pragma unroll
    for (int k = 0; k < F2PH; ++k) {
        O2[g] = xs2[k * NT + t];
        if (k < F2PH - 1) STAGE_IDX_STEP()
    }
}

template <int C>
__device__ __forceinline__ void chunk(float* __restrict__ xrow, float r[49],
                                      const float* __restrict__ WQ,
                                      const float* __restrict__ WK,
                                      const float* __restrict__ WV,
                                      const float* __restrict__ Dm) {
    constexpr int CO = (C & 1) * CS;    // col offset within 14-wide row
    constexpr int RO = (C >> 1) * CS;   // global row offset (for D)
    const float* wq = WQ + C * 49;      // wave-uniform -> s_load
    const float* wk = WK + C * 49;
    const float* wv = WV + C * 49;

    // x chunk: one LDS read pass into regs (budget 512 -> no spill)
    float x[49];
#pragma unroll
    for (int i = 0; i < CS; ++i)
#pragma unroll
        for (int j = 0; j < CS; ++j)
            x[i * CS + j] = xrow[i * 14 + CO + j];

    float K[49], V[49];
#pragma unroll
    for (int j = 0; j < CS; ++j) {
        float wck[CS], wcv[CS];
#pragma unroll
        for (int k = 0; k < CS; ++k) {
            wck[k] = wk[k * CS + j];
            wcv[k] = wv[k * CS + j];
        }
#pragma unroll
        for (int i = 0; i < CS; ++i) {
            float ak = 0.f, av = 0.f;
#pragma unroll
            for (int k = 0; k < CS; ++k) {
                ak = fmaf(x[i * CS + k], wck[k], ak);
                av = fmaf(x[i * CS + k], wcv[k], av);
            }
            K[i * CS + j] = ak;
            V[i * CS + j] = av;
        }
    }

    // per output row d: q -> s -> cross(r_prev) -> o -> overwrite x slots
#pragma unroll
    for (int d = 0; d < CS; ++d) {
        const float ev = (d == 0) ? 0.2f : (d == 1) ? 0.04f : (d == 2) ? 0.008f
                        : (d == 3) ? 0.0016f : (d == 4) ? 3.2e-4f
                        : (d == 5) ? 6.4e-5f : 1.28e-5f;
        float q[CS];
#pragma unroll
        for (int j = 0; j < CS; ++j) {
            float a = 0.f;
#pragma unroll
            for (int k = 0; k < CS; ++k)
                a = fmaf(x[d * CS + k], wq[k * CS + j], a);
            q[j] = a;
        }
        float s[CS];
#pragma unroll
        for (int k = 0; k < CS; ++k) {
            float a = 0.f;
#pragma unroll
            for (int j = 0; j < CS; ++j) a = fmaf(q[j], K[k * CS + j], a);
            s[k] = a * Dm[(RO + d) * 14 + CO + k];   // uniform -> s_load
        }
        float o[CS];
#pragma unroll
        for (int v = 0; v < CS; ++v) {
            float a = 0.f;
#pragma unroll
            for (int j = 0; j < CS; ++j) a = fmaf(q[j], r[j * CS + v], a);
            o[v] = ev * a;
        }
#pragma unroll
        for (int k = 0; k < CS; ++k)
#pragma unroll
            for (int v = 0; v < CS; ++v)
                o[v] = fmaf(s[k], V[k * CS + v], o[v]);
#pragma unroll
        for (int v = 0; v < CS; ++v)
            xrow[d * 14 + CO + v] = o[v];   // dead x slots (in-order DS)
    }

    // r += K^T V
#pragma unroll
    for (int dd = 0; dd < CS; ++dd)
#pragma unroll
        for (int v = 0; v < CS; ++v) {
            float a = r[dd * CS + v];
#pragma unroll
            for (int k = 0; k < CS; ++k)
                a = fmaf(K[k * CS + dd], V[k * CS + v], a);
            r[dd * CS + v] = a;
        }
}

__global__ __launch_bounds__(NT)
__attribute__((amdgpu_waves_per_eu(1, 1)))   // budget 512 -> zero spill
void retention_kernel(const float* __restrict__ X,
                      const float* __restrict__ WQ,
                      const float* __restrict__ WK,
                      const float* __restrict__ WV,
                      const float* __restrict__ Dm,
                      float* __restrict__ Out) {
    __shared__ float xs[NT * LDSW];   // 25088 B
    const int t = threadIdx.x;
    const size_t breg = (size_t)blockIdx.x * (NT * F2PH * 2);  // float2 units
    const float2* X2 = reinterpret_cast<const float2*>(X) + breg;
    float2*       O2 = reinterpret_cast<float2*>(Out) + breg;
    float2* xs2 = reinterpret_cast<float2*>(xs);
    float* xrow = xs + t * LDSW;

    float r[49];
#pragma unroll
    for (int i = 0; i < 49; ++i) r[i] = 0.f;

    load_half<0>(X2, xs2, t);

    // prefetch half 1 into regs: in flight during chunk0/chunk1 compute
    float2 nb[F2PH];
    load_regs<1>(X2, nb, t);

    chunk<0>(xrow, r, WQ, WK, WV, Dm);
    chunk<1>(xrow, r, WQ, WK, WV, Dm);
    store_half<0>(O2, xs2, t);

    write_half(xs2, nb, t);   // after store's DS reads (same-wave in-order)

    chunk<2>(xrow, r, WQ, WK, WV, Dm);
    chunk<3>(xrow, r, WQ, WK, WV, Dm);
    store_half<1>(O2, xs2, t);
}

extern "C" void kernel_launch(void* const* d_in, const int* in_sizes, int n_in,
                              void* d_out, int out_size, void* d_ws, size_t ws_size,
                              hipStream_t stream) {
    const float* X  = (const float*)d_in[0];
    const float* WQ = (const float*)d_in[1];
    const float* WK = (const float*)d_in[2];
    const float* WV = (const float*)d_in[3];
    const float* Dm = (const float*)d_in[4];
    float* Out = (float*)d_out;

    int B = in_sizes[0] / 196;   // 131072, divisible by 64
    int grid = B / NT;
    retention_kernel<<<grid, NT, 0, stream>>>(X, WQ, WK, WV, Dm, Out);
}